// Round 9
// baseline (235.423 us; speedup 1.0000x reference)
//
#include <hip/hip_runtime.h>
#include <cstdint>
#include <cstddef>

// Problem constants (from reference): B=2, T=2048, C=1024, H=16, hs=64
// Harness dtypes: inputs fp32, output fp32; internal compute bf16 MFMA.
#define BB 2
#define TT 2048
#define CC 1024
#define HH 16
#define HS 64
#define MM (BB*TT)      // 4096 rows
#define N1 (3*CC)       // 3072 qkv cols

// P-scratch row stride in elements (80 B/row)
#define PST2 40

// q prescale: hs^-0.5 * log2(e)  -> softmax_e(s) == softmax_2(s*log2e)
#define QSCALE 0.1803368801111243f

typedef __bf16 bf16_t;
typedef bf16_t bf16x8 __attribute__((ext_vector_type(8)));
typedef float  floatx4 __attribute__((ext_vector_type(4)));

__device__ __forceinline__ bf16_t f2bf(float f) {
    uint32_t u = __builtin_bit_cast(uint32_t, f);
    u += 0x7FFFu + ((u >> 16) & 1u);   // round-to-nearest-even
    unsigned short s = (unsigned short)(u >> 16);
    return __builtin_bit_cast(bf16_t, s);
}

__device__ __forceinline__ void load_lds16(const bf16_t* g, bf16_t* l) {
    __builtin_amdgcn_global_load_lds((__attribute__((address_space(1))) void*)g,
                                     (__attribute__((address_space(3))) void*)l,
                                     16, 0, 0);
}

// ---------------------------------------------------------------- pack x
__global__ __launch_bounds__(256) void k_pack(const float* __restrict__ src,
                                              bf16_t* __restrict__ dst) {
    size_t i = ((size_t)blockIdx.x * 256 + threadIdx.x) * 8;
    float4 a = *(const float4*)(src + i);
    float4 b = *(const float4*)(src + i + 4);
    bf16x8 o;
    o[0] = f2bf(a.x); o[1] = f2bf(a.y); o[2] = f2bf(a.z); o[3] = f2bf(a.w);
    o[4] = f2bf(b.x); o[5] = f2bf(b.y); o[6] = f2bf(b.z); o[7] = f2bf(b.w);
    *(bf16x8*)(dst + i) = o;
}

// ---------------------------------------------------------------- transpose+cvt
__global__ __launch_bounds__(256) void k_transpose(const float* __restrict__ src,
                                                   bf16_t* __restrict__ dst,
                                                   int R, int Ccol) {
    __shared__ bf16_t tile[32][33];
    int c0 = blockIdx.x * 32, r0 = blockIdx.y * 32;
    int tx = threadIdx.x, ty = threadIdx.y;
    for (int i = ty; i < 32; i += 8)
        tile[i][tx] = f2bf(src[(size_t)(r0 + i) * Ccol + c0 + tx]);
    __syncthreads();
    for (int i = ty; i < 32; i += 8)
        dst[(size_t)(c0 + i) * R + r0 + tx] = tile[tx][i];
}

// ---------------------------------------------------------------- GEMM core
__device__ __forceinline__ void gemm_core(const bf16_t* __restrict__ A,
                                          const bf16_t* __restrict__ Bt,
                                          bf16_t* As, bf16_t* Bs,
                                          int m0, int n0, int K,
                                          floatx4 acc[4][4]) {
    const int tid = threadIdx.x;
    const int wave = tid >> 6, lane = tid & 63;
    const int quad = lane >> 4, lrow = lane & 15;
    const int wm = wave >> 1, wn = wave & 1;
    const int lsub = lane >> 2;
    const int kc = lane & 3;

    for (int kk = 0; kk < K; kk += 32) {
        for (int s = 0; s < 2; ++s) {
            int rg = wave * 2 + s;
            const bf16_t* ga = A  + (size_t)(m0 + rg * 16 + lsub) * K + kk + kc * 8;
            const bf16_t* gb = Bt + (size_t)(n0 + rg * 16 + lsub) * K + kk + kc * 8;
            load_lds16(ga, As + rg * 512);
            load_lds16(gb, Bs + rg * 512);
        }
        __syncthreads();
        bf16x8 af[4], bfr[4];
        for (int i = 0; i < 4; ++i)
            af[i] = *(const bf16x8*)(As + (wm * 64 + i * 16 + lrow) * 32 + quad * 8);
        for (int j = 0; j < 4; ++j)
            bfr[j] = *(const bf16x8*)(Bs + (wn * 64 + j * 16 + lrow) * 32 + quad * 8);
        for (int i = 0; i < 4; ++i)
            for (int j = 0; j < 4; ++j)
                acc[i][j] = __builtin_amdgcn_mfma_f32_16x16x32_bf16(af[i], bfr[j], acc[i][j], 0, 0, 0);
        __syncthreads();
    }
}

// ---------------------------------------------------------------- QKV GEMM
__global__ __launch_bounds__(256, 2) void k_gemm_qkv(const bf16_t* __restrict__ x,
                                                     const bf16_t* __restrict__ Wt,
                                                     bf16_t* __restrict__ qb,
                                                     bf16_t* __restrict__ kb,
                                                     bf16_t* __restrict__ vn) {
    __shared__ bf16_t As[128 * 32];
    __shared__ bf16_t Bs[128 * 32];
    const int m0 = blockIdx.y * 128, n0 = blockIdx.x * 128;
    floatx4 acc[4][4];
    for (int i = 0; i < 4; ++i)
        for (int j = 0; j < 4; ++j)
            acc[i][j] = floatx4{0.f, 0.f, 0.f, 0.f};
    gemm_core(x, Wt, As, Bs, m0, n0, CC, acc);

    const int tid = threadIdx.x, wave = tid >> 6, lane = tid & 63;
    const int quad = lane >> 4, lrow = lane & 15;
    const int wm = wave >> 1, wn = wave & 1;
    for (int i = 0; i < 4; ++i)
        for (int j = 0; j < 4; ++j) {
            int gn = n0 + wn * 64 + j * 16 + lrow;
            int which = gn >> 10, c = gn & 1023, h = c >> 6, d = c & 63;
            for (int r = 0; r < 4; ++r) {
                int gm = m0 + wm * 64 + i * 16 + quad * 4 + r;
                int b = gm >> 11, t = gm & 2047;
                float val = acc[i][j][r];
                if (which == 0)
                    qb[((size_t)(b * HH + h) * TT + t) * HS + d] = f2bf(val * QSCALE);
                else if (which == 1)
                    kb[((size_t)(b * HH + h) * TT + t) * HS + d] = f2bf(val);
                else
                    vn[((size_t)(b * HH + h) * TT + t) * HS + d] = f2bf(val);
            }
        }
}

// ---------------------------------------------------------------- V permute
// vn[B,H,T,hs] -> vt[B,H,hs,T] with per-32 key interleave sigma(u)=(u&15)*2+(u>>4).
__global__ __launch_bounds__(256) void k_vperm(const bf16_t* __restrict__ vn,
                                               bf16_t* __restrict__ vt) {
    __shared__ bf16_t tile[64][72];
    const int tid = threadIdx.x;
    const int bh = blockIdx.x & 31, tb = blockIdx.x >> 5;
    const bf16_t* src = vn + ((size_t)bh * TT + tb * 64) * HS;

    for (int h = 0; h < 2; ++h) {
        int r = (tid >> 3) + h * 32;
        int c8 = (tid & 7) * 8;
        *(bf16x8*)(&tile[r][c8]) = *(const bf16x8*)(src + (size_t)r * HS + c8);
    }
    __syncthreads();

    bf16_t* dst = vt + (size_t)bh * HS * TT + tb * 64;
    const int a   = tid & 15;
    const int blk = ((tid >> 4) & 1) * 32;
    const int dg  = tid >> 5;
    for (int k = 0; k < 8; ++k) {
        int d = dg * 8 + k;
        uint32_t lo = (uint32_t)__builtin_bit_cast(unsigned short, tile[blk + a][d]);
        uint32_t hi = (uint32_t)__builtin_bit_cast(unsigned short, tile[blk + a + 16][d]);
        *(uint32_t*)(dst + (size_t)d * TT + blk + 2 * a) = lo | (hi << 16);
    }
}

// ---------------------------------------------------------------- attention (flash-decoding partials)
// Block = 2 waves = 64 queries (qg) x ONE key chunk (kc, <=8 32-key tiles).
// No-max softmax => partials are ADDITIVE: unnormalized o and l just sum
// across chunks (atomicAdd fp32). l computed via ones-MFMA (row-sum of the
// SAME bf16 P used for PV, so quantization cancels in o/l). P packed by
// truncation (no rounding adds). R8 cooperative double-buffered staging.
__global__ __launch_bounds__(128, 2) void k_attn(const bf16_t* __restrict__ qb,
                                                 const bf16_t* __restrict__ kb,
                                                 const bf16_t* __restrict__ vt,
                                                 float* __restrict__ o_accum,
                                                 float* __restrict__ l_acc) {
    __shared__ bf16_t Kb[2][32 * 72];   // key row stride 72 elem (144B)
    __shared__ bf16_t Vb[2][64 * 40];   // d row stride 40 elem (80B)
    __shared__ bf16_t Ps[2][32 * PST2]; // per-wave 32-row P scratch
    const int tid = threadIdx.x;
    const int w = tid >> 6, lane = tid & 63;
    const int quad = lane >> 4, lrow = lane & 15;
    const int bh = blockIdx.x & 31;
    const int j = blockIdx.x >> 5;                 // 0..143
    // invert j -> (qg, kc): qg in [4s,4s+3] has s+1 chunks; offset 2s(s+1)
    int s = 0;
    #pragma unroll
    for (int ss = 0; ss < 7; ++ss) if (j >= 2 * (ss + 2) * (ss + 1)) s = ss + 1;
    const int rem = j - 2 * s * (s + 1);
    const int qg = 4 * s + rem / (s + 1);
    const int kc = rem - (rem / (s + 1)) * (s + 1);

    const int q0 = qg * 64 + w * 32;
    const int key0 = kc * 256;
    const int ct = min(8, qg * 2 + 2 - kc * 8);    // block trip count
    const int kendl = qg * 2 + w + 1 - kc * 8;     // wave tiles (may exceed ct)
    const int kw = min(kendl, ct);

    const bf16_t* Qg = qb + (size_t)bh * TT * HS;
    const bf16_t* Kg = kb + (size_t)bh * TT * HS;
    const bf16_t* Vg = vt + (size_t)bh * HS * TT;

    const int skey = tid >> 2, scol = (tid & 3) * 16;
    const int svrow = tid >> 1, svcol = (tid & 1) * 16;

    bf16x8 kra, krb, vra, vrb;
    {   // prestage tile 0
        const bf16_t* gk = Kg + (size_t)(key0 + skey) * HS + scol;
        kra = *(const bf16x8*)(gk);
        krb = *(const bf16x8*)(gk + 8);
        const bf16_t* gv = Vg + (size_t)svrow * TT + key0 + svcol;
        vra = *(const bf16x8*)(gv);
        vrb = *(const bf16x8*)(gv + 8);
        *(bf16x8*)(&Kb[0][skey * 72 + scol])     = kra;
        *(bf16x8*)(&Kb[0][skey * 72 + scol + 8]) = krb;
        *(bf16x8*)(&Vb[0][svrow * 40 + svcol])     = vra;
        *(bf16x8*)(&Vb[0][svrow * 40 + svcol + 8]) = vrb;
    }

    bf16x8 aq[2][2];
    for (int tq = 0; tq < 2; ++tq)
        for (int c = 0; c < 2; ++c)
            aq[tq][c] = *(const bf16x8*)(Qg + (size_t)(q0 + tq * 16 + lrow) * HS + c * 32 + quad * 8);

    const bf16_t onebf = __builtin_bit_cast(bf16_t, (unsigned short)0x3F80);
    bf16x8 bones = {onebf, onebf, onebf, onebf, onebf, onebf, onebf, onebf};

    floatx4 o[2][4];
    for (int tq = 0; tq < 2; ++tq)
        for (int dc = 0; dc < 4; ++dc) o[tq][dc] = floatx4{0.f, 0.f, 0.f, 0.f};
    floatx4 ol[2] = {floatx4{0.f,0.f,0.f,0.f}, floatx4{0.f,0.f,0.f,0.f}};

    uint32_t* P32 = (uint32_t*)(&Ps[w][0]);
    const bf16_t* Pr = &Ps[w][0];
    const int wrow0 = quad * 4;

    for (int t = 0; t < ct; ++t) {
        __syncthreads();
        if (t + 1 < ct) {   // post-barrier prefetch of next tile
            const bf16_t* gk = Kg + (size_t)(key0 + (t + 1) * 32 + skey) * HS + scol;
            kra = *(const bf16x8*)(gk);
            krb = *(const bf16x8*)(gk + 8);
            const bf16_t* gv = Vg + (size_t)svrow * TT + key0 + (t + 1) * 32 + svcol;
            vra = *(const bf16x8*)(gv);
            vrb = *(const bf16x8*)(gv + 8);
        }
        if (t < kw) {
            const bf16_t* Kt = &Kb[t & 1][0];
            const bf16_t* Vt = &Vb[t & 1][0];
            bf16x8 bk0 = *(const bf16x8*)(Kt + lrow * 72 + quad * 8);
            bf16x8 bk1 = *(const bf16x8*)(Kt + lrow * 72 + 32 + quad * 8);
            bf16x8 bk2 = *(const bf16x8*)(Kt + (16 + lrow) * 72 + quad * 8);
            bf16x8 bk3 = *(const bf16x8*)(Kt + (16 + lrow) * 72 + 32 + quad * 8);
            floatx4 s00 = floatx4{0.f,0.f,0.f,0.f}, s01 = s00, s10 = s00, s11 = s00;
            s00 = __builtin_amdgcn_mfma_f32_16x16x32_bf16(aq[0][0], bk0, s00, 0, 0, 0);
            s00 = __builtin_amdgcn_mfma_f32_16x16x32_bf16(aq[0][1], bk1, s00, 0, 0, 0);
            s01 = __builtin_amdgcn_mfma_f32_16x16x32_bf16(aq[0][0], bk2, s01, 0, 0, 0);
            s01 = __builtin_amdgcn_mfma_f32_16x16x32_bf16(aq[0][1], bk3, s01, 0, 0, 0);
            s10 = __builtin_amdgcn_mfma_f32_16x16x32_bf16(aq[1][0], bk0, s10, 0, 0, 0);
            s10 = __builtin_amdgcn_mfma_f32_16x16x32_bf16(aq[1][1], bk1, s10, 0, 0, 0);
            s11 = __builtin_amdgcn_mfma_f32_16x16x32_bf16(aq[1][0], bk2, s11, 0, 0, 0);
            s11 = __builtin_amdgcn_mfma_f32_16x16x32_bf16(aq[1][1], bk3, s11, 0, 0, 0);

            bf16x8 bv0 = *(const bf16x8*)(Vt + (0  + lrow) * 40 + quad * 8);
            bf16x8 bv1 = *(const bf16x8*)(Vt + (16 + lrow) * 40 + quad * 8);
            bf16x8 bv2 = *(const bf16x8*)(Vt + (32 + lrow) * 40 + quad * 8);
            bf16x8 bv3 = *(const bf16x8*)(Vt + (48 + lrow) * 40 + quad * 8);

            if (t < kendl - 1) {            // unmasked tile
                for (int r = 0; r < 4; ++r) {
                    float e00 = __builtin_amdgcn_exp2f(s00[r]);
                    float e01 = __builtin_amdgcn_exp2f(s01[r]);
                    float e10 = __builtin_amdgcn_exp2f(s10[r]);
                    float e11 = __builtin_amdgcn_exp2f(s11[r]);
                    uint32_t pk0 = __builtin_amdgcn_perm(
                        __builtin_bit_cast(uint32_t, e01),
                        __builtin_bit_cast(uint32_t, e00), 0x07060302u);
                    uint32_t pk1 = __builtin_amdgcn_perm(
                        __builtin_bit_cast(uint32_t, e11),
                        __builtin_bit_cast(uint32_t, e10), 0x07060302u);
                    P32[(wrow0 + r) * 20 + lrow]      = pk0;
                    P32[(wrow0 + r + 16) * 20 + lrow] = pk1;
                }
            } else {                        // diagonal tile (keys start at q0)
                for (int r = 0; r < 4; ++r) {
                    bool keep = lrow <= quad * 4 + r;
                    float e00 = keep ? __builtin_amdgcn_exp2f(s00[r]) : 0.f;
                    float e01 = 0.f; (void)s01;
                    float e10 = __builtin_amdgcn_exp2f(s10[r]);
                    float e11 = keep ? __builtin_amdgcn_exp2f(s11[r]) : 0.f;
                    uint32_t pk0 = __builtin_amdgcn_perm(
                        __builtin_bit_cast(uint32_t, e01),
                        __builtin_bit_cast(uint32_t, e00), 0x07060302u);
                    uint32_t pk1 = __builtin_amdgcn_perm(
                        __builtin_bit_cast(uint32_t, e11),
                        __builtin_bit_cast(uint32_t, e10), 0x07060302u);
                    P32[(wrow0 + r) * 20 + lrow]      = pk0;
                    P32[(wrow0 + r + 16) * 20 + lrow] = pk1;
                }
            }
            asm volatile("s_waitcnt lgkmcnt(0)" ::: "memory");  // wave-local P RAW

            bf16x8 pa0 = *(const bf16x8*)(Pr + (size_t)lrow * PST2 + quad * 8);
            bf16x8 pa1 = *(const bf16x8*)(Pr + (size_t)(16 + lrow) * PST2 + quad * 8);
            o[0][0] = __builtin_amdgcn_mfma_f32_16x16x32_bf16(pa0, bv0, o[0][0], 0, 0, 0);
            o[0][1] = __builtin_amdgcn_mfma_f32_16x16x32_bf16(pa0, bv1, o[0][1], 0, 0, 0);
            o[0][2] = __builtin_amdgcn_mfma_f32_16x16x32_bf16(pa0, bv2, o[0][2], 0, 0, 0);
            o[0][3] = __builtin_amdgcn_mfma_f32_16x16x32_bf16(pa0, bv3, o[0][3], 0, 0, 0);
            ol[0]   = __builtin_amdgcn_mfma_f32_16x16x32_bf16(pa0, bones, ol[0], 0, 0, 0);
            o[1][0] = __builtin_amdgcn_mfma_f32_16x16x32_bf16(pa1, bv0, o[1][0], 0, 0, 0);
            o[1][1] = __builtin_amdgcn_mfma_f32_16x16x32_bf16(pa1, bv1, o[1][1], 0, 0, 0);
            o[1][2] = __builtin_amdgcn_mfma_f32_16x16x32_bf16(pa1, bv2, o[1][2], 0, 0, 0);
            o[1][3] = __builtin_amdgcn_mfma_f32_16x16x32_bf16(pa1, bv3, o[1][3], 0, 0, 0);
            ol[1]   = __builtin_amdgcn_mfma_f32_16x16x32_bf16(pa1, bones, ol[1], 0, 0, 0);
        }
        if (t + 1 < ct) {
            bf16_t* Kn = &Kb[(t + 1) & 1][0];
            bf16_t* Vn = &Vb[(t + 1) & 1][0];
            *(bf16x8*)(Kn + skey * 72 + scol)     = kra;
            *(bf16x8*)(Kn + skey * 72 + scol + 8) = krb;
            *(bf16x8*)(Vn + svrow * 40 + svcol)     = vra;
            *(bf16x8*)(Vn + svrow * 40 + svcol + 8) = vrb;
        }
    }

    // additive epilogue: atomicAdd partial o and l
    for (int tq = 0; tq < 2; ++tq)
        for (int r = 0; r < 4; ++r) {
            int q = q0 + tq * 16 + quad * 4 + r;
            float* dst = o_accum + ((size_t)bh * TT + q) * HS + lrow;
            for (int dc = 0; dc < 4; ++dc)
                atomicAdd(dst + dc * 16, o[tq][dc][r]);
            if (lrow == 0)
                atomicAdd(l_acc + (size_t)bh * TT + q, ol[tq][r]);
        }
}

// ---------------------------------------------------------------- normalize
// yb[b,t,C] = o_accum[bh,q,d] / l[bh,q], bf16. 8 d-elems/thread.
__global__ __launch_bounds__(256) void k_norm(const float* __restrict__ o_accum,
                                              const float* __restrict__ l_acc,
                                              bf16_t* __restrict__ yb) {
    int idx = blockIdx.x * 256 + threadIdx.x;      // over 32*2048*8
    int d8 = idx & 7;
    int q  = (idx >> 3) & (TT - 1);
    int bh = idx >> 14;
    float inv = 1.0f / l_acc[(size_t)bh * TT + q];
    const float* src = o_accum + ((size_t)bh * TT + q) * HS + d8 * 8;
    float4 a = *(const float4*)(src);
    float4 b = *(const float4*)(src + 4);
    bf16x8 r;
    r[0] = f2bf(a.x * inv); r[1] = f2bf(a.y * inv);
    r[2] = f2bf(a.z * inv); r[3] = f2bf(a.w * inv);
    r[4] = f2bf(b.x * inv); r[5] = f2bf(b.y * inv);
    r[6] = f2bf(b.z * inv); r[7] = f2bf(b.w * inv);
    int bb = bh >> 4, h = bh & 15;
    *(bf16x8*)(yb + ((size_t)(bb * TT + q)) * CC + h * HS + d8 * 8) = r;
}

// ---------------------------------------------------------------- out GEMM (fp32 out + bias)
__global__ __launch_bounds__(256, 2) void k_gemm_out(const bf16_t* __restrict__ yin,
                                                     const bf16_t* __restrict__ Wt,
                                                     const float* __restrict__ bias,
                                                     float* __restrict__ out) {
    __shared__ bf16_t As[128 * 32];
    __shared__ bf16_t Bs[128 * 32];
    const int m0 = blockIdx.y * 128, n0 = blockIdx.x * 128;
    floatx4 acc[4][4];
    for (int i = 0; i < 4; ++i)
        for (int j = 0; j < 4; ++j)
            acc[i][j] = floatx4{0.f, 0.f, 0.f, 0.f};
    gemm_core(yin, Wt, As, Bs, m0, n0, CC, acc);

    const int tid = threadIdx.x, wave = tid >> 6, lane = tid & 63;
    const int quad = lane >> 4, lrow = lane & 15;
    const int wm = wave >> 1, wn = wave & 1;
    for (int i = 0; i < 4; ++i)
        for (int j = 0; j < 4; ++j) {
            int gn = n0 + wn * 64 + j * 16 + lrow;
            float bb = bias[gn];
            for (int r = 0; r < 4; ++r) {
                int gm = m0 + wm * 64 + i * 16 + quad * 4 + r;
                out[(size_t)gm * CC + gn] = acc[i][j][r] + bb;
            }
        }
}

// ---------------------------------------------------------------- launch
extern "C" void kernel_launch(void* const* d_in, const int* in_sizes, int n_in,
                              void* d_out, int out_size, void* d_ws, size_t ws_size,
                              hipStream_t stream) {
    (void)in_sizes; (void)n_in; (void)out_size; (void)ws_size;
    const float* x    = (const float*)d_in[0];  // [2,2048,1024] fp32
    const float* Wqkv = (const float*)d_in[1];  // [1024,3072]   fp32
    const float* Wout = (const float*)d_in[2];  // [1024,1024]   fp32
    const float* bout = (const float*)d_in[3];  // [1024]        fp32
    float* out = (float*)d_out;                 // [2,2048,1024] fp32

    bf16_t* xb  = (bf16_t*)d_ws;                        // [4096][1024]  8 MB
    bf16_t* Wt1 = xb + (size_t)MM * CC;                 // [3072][1024]  6 MB
    bf16_t* Wt2 = Wt1 + (size_t)N1 * CC;                // [1024][1024]  2 MB
    bf16_t* qb  = Wt2 + (size_t)CC * CC;                // [B,H,T,hs]    8 MB
    bf16_t* kb  = qb + (size_t)BB * HH * TT * HS;       // [B,H,T,hs]    8 MB
    bf16_t* vb  = kb + (size_t)BB * HH * TT * HS;       // [B,H,hs,T~]   8 MB (perm)
    bf16_t* yb  = vb + (size_t)BB * HH * TT * HS;       // [B,T,C] bf16  8 MB
    bf16_t* vn  = yb;            // natural V; dead after k_vperm, before yb born
    float*  o_accum = (float*)d_out;   // 16 MB scratch; dead before k_gemm_out writes
    float*  l_acc   = (float*)Wt1;     // 256 KB; Wt1 dead after k_gemm_qkv

    k_pack<<<dim3((size_t)MM * CC / (256 * 8)), 256, 0, stream>>>(x, xb);
    k_transpose<<<dim3(N1 / 32, CC / 32), dim3(32, 8), 0, stream>>>(Wqkv, Wt1, CC, N1);
    k_transpose<<<dim3(CC / 32, CC / 32), dim3(32, 8), 0, stream>>>(Wout, Wt2, CC, CC);
    k_gemm_qkv<<<dim3(N1 / 128, MM / 128), 256, 0, stream>>>(xb, Wt1, qb, kb, vn);
    // zero accumulators (stream-ordered: after gemm_qkv consumed Wt1)
    hipMemsetAsync(o_accum, 0, (size_t)MM * CC * sizeof(float), stream);
    hipMemsetAsync(l_acc, 0, (size_t)BB * HH * TT * sizeof(float), stream);
    k_vperm<<<dim3(32 * 32), 256, 0, stream>>>(vn, vb);
    k_attn<<<dim3(144 * 32), 128, 0, stream>>>(qb, kb, vb, o_accum, l_acc);
    k_norm<<<dim3(BB * HH * TT * 8 / 256), 256, 0, stream>>>(o_accum, l_acc, yb);
    k_gemm_out<<<dim3(CC / 128, MM / 128), 256, 0, stream>>>(yb, Wt2, bout, out);
}

// Round 10
// 190.377 us; speedup vs baseline: 1.2366x; 1.2366x over previous
//
#include <hip/hip_runtime.h>
#include <cstdint>
#include <cstddef>

// Problem constants (from reference): B=2, T=2048, C=1024, H=16, hs=64
// Harness dtypes: inputs fp32, output fp32; internal compute bf16 MFMA.
#define BB 2
#define TT 2048
#define CC 1024
#define HH 16
#define HS 64
#define MM (BB*TT)      // 4096 rows
#define N1 (3*CC)       // 3072 qkv cols

// P-scratch row stride in elements (80 B/row)
#define PST2 40

// q prescale: hs^-0.5 * log2(e)  -> softmax_e(s) == softmax_2(s*log2e)
#define QSCALE 0.1803368801111243f

typedef __bf16 bf16_t;
typedef bf16_t bf16x8 __attribute__((ext_vector_type(8)));
typedef float  floatx4 __attribute__((ext_vector_type(4)));

__device__ __forceinline__ bf16_t f2bf(float f) {
    uint32_t u = __builtin_bit_cast(uint32_t, f);
    u += 0x7FFFu + ((u >> 16) & 1u);   // round-to-nearest-even
    unsigned short s = (unsigned short)(u >> 16);
    return __builtin_bit_cast(bf16_t, s);
}

__device__ __forceinline__ void load_lds16(const bf16_t* g, bf16_t* l) {
    __builtin_amdgcn_global_load_lds((__attribute__((address_space(1))) void*)g,
                                     (__attribute__((address_space(3))) void*)l,
                                     16, 0, 0);
}

// ---------------------------------------------------------------- pack x
__global__ __launch_bounds__(256) void k_pack(const float* __restrict__ src,
                                              bf16_t* __restrict__ dst) {
    size_t i = ((size_t)blockIdx.x * 256 + threadIdx.x) * 8;
    float4 a = *(const float4*)(src + i);
    float4 b = *(const float4*)(src + i + 4);
    bf16x8 o;
    o[0] = f2bf(a.x); o[1] = f2bf(a.y); o[2] = f2bf(a.z); o[3] = f2bf(a.w);
    o[4] = f2bf(b.x); o[5] = f2bf(b.y); o[6] = f2bf(b.z); o[7] = f2bf(b.w);
    *(bf16x8*)(dst + i) = o;
}

// ---------------------------------------------------------------- transpose+cvt
__global__ __launch_bounds__(256) void k_transpose(const float* __restrict__ src,
                                                   bf16_t* __restrict__ dst,
                                                   int R, int Ccol) {
    __shared__ bf16_t tile[32][33];
    int c0 = blockIdx.x * 32, r0 = blockIdx.y * 32;
    int tx = threadIdx.x, ty = threadIdx.y;
    for (int i = ty; i < 32; i += 8)
        tile[i][tx] = f2bf(src[(size_t)(r0 + i) * Ccol + c0 + tx]);
    __syncthreads();
    for (int i = ty; i < 32; i += 8)
        dst[(size_t)(c0 + i) * R + r0 + tx] = tile[tx][i];
}

// ---------------------------------------------------------------- GEMM core
__device__ __forceinline__ void gemm_core(const bf16_t* __restrict__ A,
                                          const bf16_t* __restrict__ Bt,
                                          bf16_t* As, bf16_t* Bs,
                                          int m0, int n0, int K,
                                          floatx4 acc[4][4]) {
    const int tid = threadIdx.x;
    const int wave = tid >> 6, lane = tid & 63;
    const int quad = lane >> 4, lrow = lane & 15;
    const int wm = wave >> 1, wn = wave & 1;
    const int lsub = lane >> 2;
    const int kc = lane & 3;

    for (int kk = 0; kk < K; kk += 32) {
        for (int s = 0; s < 2; ++s) {
            int rg = wave * 2 + s;
            const bf16_t* ga = A  + (size_t)(m0 + rg * 16 + lsub) * K + kk + kc * 8;
            const bf16_t* gb = Bt + (size_t)(n0 + rg * 16 + lsub) * K + kk + kc * 8;
            load_lds16(ga, As + rg * 512);
            load_lds16(gb, Bs + rg * 512);
        }
        __syncthreads();
        bf16x8 af[4], bfr[4];
        for (int i = 0; i < 4; ++i)
            af[i] = *(const bf16x8*)(As + (wm * 64 + i * 16 + lrow) * 32 + quad * 8);
        for (int j = 0; j < 4; ++j)
            bfr[j] = *(const bf16x8*)(Bs + (wn * 64 + j * 16 + lrow) * 32 + quad * 8);
        for (int i = 0; i < 4; ++i)
            for (int j = 0; j < 4; ++j)
                acc[i][j] = __builtin_amdgcn_mfma_f32_16x16x32_bf16(af[i], bfr[j], acc[i][j], 0, 0, 0);
        __syncthreads();
    }
}

// ---------------------------------------------------------------- QKV GEMM
__global__ __launch_bounds__(256, 2) void k_gemm_qkv(const bf16_t* __restrict__ x,
                                                     const bf16_t* __restrict__ Wt,
                                                     bf16_t* __restrict__ qb,
                                                     bf16_t* __restrict__ kb,
                                                     bf16_t* __restrict__ vn) {
    __shared__ bf16_t As[128 * 32];
    __shared__ bf16_t Bs[128 * 32];
    const int m0 = blockIdx.y * 128, n0 = blockIdx.x * 128;
    floatx4 acc[4][4];
    for (int i = 0; i < 4; ++i)
        for (int j = 0; j < 4; ++j)
            acc[i][j] = floatx4{0.f, 0.f, 0.f, 0.f};
    gemm_core(x, Wt, As, Bs, m0, n0, CC, acc);

    const int tid = threadIdx.x, wave = tid >> 6, lane = tid & 63;
    const int quad = lane >> 4, lrow = lane & 15;
    const int wm = wave >> 1, wn = wave & 1;
    for (int i = 0; i < 4; ++i)
        for (int j = 0; j < 4; ++j) {
            int gn = n0 + wn * 64 + j * 16 + lrow;
            int which = gn >> 10, c = gn & 1023, h = c >> 6, d = c & 63;
            for (int r = 0; r < 4; ++r) {
                int gm = m0 + wm * 64 + i * 16 + quad * 4 + r;
                int b = gm >> 11, t = gm & 2047;
                float val = acc[i][j][r];
                if (which == 0)
                    qb[((size_t)(b * HH + h) * TT + t) * HS + d] = f2bf(val * QSCALE);
                else if (which == 1)
                    kb[((size_t)(b * HH + h) * TT + t) * HS + d] = f2bf(val);
                else
                    vn[((size_t)(b * HH + h) * TT + t) * HS + d] = f2bf(val);
            }
        }
}

// ---------------------------------------------------------------- V permute
// vn[B,H,T,hs] -> vt[B,H,hs,T] with per-32 key interleave sigma(u)=(u&15)*2+(u>>4).
__global__ __launch_bounds__(256) void k_vperm(const bf16_t* __restrict__ vn,
                                               bf16_t* __restrict__ vt) {
    __shared__ bf16_t tile[64][72];
    const int tid = threadIdx.x;
    const int bh = blockIdx.x & 31, tb = blockIdx.x >> 5;
    const bf16_t* src = vn + ((size_t)bh * TT + tb * 64) * HS;

    for (int h = 0; h < 2; ++h) {
        int r = (tid >> 3) + h * 32;
        int c8 = (tid & 7) * 8;
        *(bf16x8*)(&tile[r][c8]) = *(const bf16x8*)(src + (size_t)r * HS + c8);
    }
    __syncthreads();

    bf16_t* dst = vt + (size_t)bh * HS * TT + tb * 64;
    const int a   = tid & 15;
    const int blk = ((tid >> 4) & 1) * 32;
    const int dg  = tid >> 5;
    for (int k = 0; k < 8; ++k) {
        int d = dg * 8 + k;
        uint32_t lo = (uint32_t)__builtin_bit_cast(unsigned short, tile[blk + a][d]);
        uint32_t hi = (uint32_t)__builtin_bit_cast(unsigned short, tile[blk + a + 16][d]);
        *(uint32_t*)(dst + (size_t)d * TT + blk + 2 * a) = lo | (hi << 16);
    }
}

// block schedule: (qg, c) sorted by trip count desc; c=-1 = unsplit (qg<16)
__device__ static const signed char ORD[48][2] = {
    {15,-1},{31,0},{31,1},{30,0},{30,1},
    {14,-1},{29,0},{29,1},{28,0},{28,1},
    {13,-1},{27,0},{27,1},{26,0},{26,1},
    {12,-1},{25,0},{25,1},{24,0},{24,1},
    {11,-1},{23,0},{23,1},{22,0},{22,1},
    {10,-1},{21,0},{21,1},{20,0},{20,1},
    { 9,-1},{19,0},{19,1},{18,0},{18,1},
    { 8,-1},{17,0},{17,1},{16,0},{16,1},
    { 7,-1},{ 6,-1},{ 5,-1},{ 4,-1},{ 3,-1},{ 2,-1},{ 1,-1},{ 0,-1}
};

// ---------------------------------------------------------------- attention (partials, no atomics)
// Block = 2 waves = 64 queries (qg) x one key chunk. qg<16: whole range ->
// partial buf 0. qg>=16: split in two; c=0 (front half, unmasked) -> buf 0,
// c=1 (back half incl diagonal) -> buf 1. Exactly one writer per slot ->
// plain stores, no atomics/memsets. No-max softmax => partials sum in k_norm.
// P software-pipelined one tile (ping-pong parity buffers): iter t does
// PV(t-1), then QK(t)/exp/P-write -- no in-loop lgkmcnt(0). l via ones-MFMA.
__global__ __launch_bounds__(128, 2) void k_attn(const bf16_t* __restrict__ qb,
                                                 const bf16_t* __restrict__ kb,
                                                 const bf16_t* __restrict__ vt,
                                                 float* __restrict__ o0,
                                                 float* __restrict__ o1,
                                                 float* __restrict__ l0,
                                                 float* __restrict__ l1) {
    __shared__ bf16_t Kb[2][32 * 72];      // key row stride 144B
    __shared__ bf16_t Vb[2][64 * 40];      // d row stride 80B
    __shared__ bf16_t Ps[2][2][32 * PST2]; // [wave][parity]
    const int tid = threadIdx.x;
    const int w = tid >> 6, lane = tid & 63;
    const int quad = lane >> 4, lrow = lane & 15;
    const int bh = blockIdx.x & 31;
    const int j = blockIdx.x >> 5;                 // 0..47
    const int qg = ORD[j][0];
    const int cc = ORD[j][1];                      // -1 = unsplit
    const int ct = (cc < 0) ? (2 * qg + 2) : (qg + 1);
    const int key0 = (cc == 1) ? (qg + 1) * 32 : 0;
    const int kendl = 2 * qg + w + 1 - ((cc == 1) ? (qg + 1) : 0);
    const int kw = min(kendl, ct);
    const int q0 = qg * 64 + w * 32;

    const bf16_t* Qg = qb + (size_t)bh * TT * HS;
    const bf16_t* Kg = kb + (size_t)bh * TT * HS;
    const bf16_t* Vg = vt + (size_t)bh * HS * TT;

    const int skey = tid >> 2, scol = (tid & 3) * 16;
    const int svrow = tid >> 1, svcol = (tid & 1) * 16;

    bf16x8 kra, krb, vra, vrb;
    {   // prestage tile 0
        const bf16_t* gk = Kg + (size_t)(key0 + skey) * HS + scol;
        kra = *(const bf16x8*)(gk);
        krb = *(const bf16x8*)(gk + 8);
        const bf16_t* gv = Vg + (size_t)svrow * TT + key0 + svcol;
        vra = *(const bf16x8*)(gv);
        vrb = *(const bf16x8*)(gv + 8);
        *(bf16x8*)(&Kb[0][skey * 72 + scol])     = kra;
        *(bf16x8*)(&Kb[0][skey * 72 + scol + 8]) = krb;
        *(bf16x8*)(&Vb[0][svrow * 40 + svcol])     = vra;
        *(bf16x8*)(&Vb[0][svrow * 40 + svcol + 8]) = vrb;
    }

    bf16x8 aq[2][2];
    for (int tq = 0; tq < 2; ++tq)
        for (int c = 0; c < 2; ++c)
            aq[tq][c] = *(const bf16x8*)(Qg + (size_t)(q0 + tq * 16 + lrow) * HS + c * 32 + quad * 8);

    const bf16_t onebf = __builtin_bit_cast(bf16_t, (unsigned short)0x3F80);
    bf16x8 bones = {onebf, onebf, onebf, onebf, onebf, onebf, onebf, onebf};

    floatx4 o[2][4];
    for (int tq = 0; tq < 2; ++tq)
        for (int dc = 0; dc < 4; ++dc) o[tq][dc] = floatx4{0.f, 0.f, 0.f, 0.f};
    floatx4 ol[2] = {floatx4{0.f,0.f,0.f,0.f}, floatx4{0.f,0.f,0.f,0.f}};

    bf16x8 bv_sav[4];
    const int wrow0 = quad * 4;

    for (int t = 0; t < ct; ++t) {
        __syncthreads();   // staging writes of t (done at end of t-1) visible
        if (t + 1 < ct) {  // post-barrier prefetch of next tile into regs
            const bf16_t* gk = Kg + (size_t)(key0 + (t + 1) * 32 + skey) * HS + scol;
            kra = *(const bf16x8*)(gk);
            krb = *(const bf16x8*)(gk + 8);
            const bf16_t* gv = Vg + (size_t)svrow * TT + key0 + (t + 1) * 32 + svcol;
            vra = *(const bf16x8*)(gv);
            vrb = *(const bf16x8*)(gv + 8);
        }
        if (t < kw) {
            // ---- deferred PV for tile t-1 (P from parity buffer, V from regs)
            if (t > 0) {
                const bf16_t* Pp = &Ps[w][(t - 1) & 1][0];
                bf16x8 pa0 = *(const bf16x8*)(Pp + (size_t)lrow * PST2 + quad * 8);
                bf16x8 pa1 = *(const bf16x8*)(Pp + (size_t)(16 + lrow) * PST2 + quad * 8);
                o[0][0] = __builtin_amdgcn_mfma_f32_16x16x32_bf16(pa0, bv_sav[0], o[0][0], 0, 0, 0);
                o[0][1] = __builtin_amdgcn_mfma_f32_16x16x32_bf16(pa0, bv_sav[1], o[0][1], 0, 0, 0);
                o[0][2] = __builtin_amdgcn_mfma_f32_16x16x32_bf16(pa0, bv_sav[2], o[0][2], 0, 0, 0);
                o[0][3] = __builtin_amdgcn_mfma_f32_16x16x32_bf16(pa0, bv_sav[3], o[0][3], 0, 0, 0);
                ol[0]   = __builtin_amdgcn_mfma_f32_16x16x32_bf16(pa0, bones, ol[0], 0, 0, 0);
                o[1][0] = __builtin_amdgcn_mfma_f32_16x16x32_bf16(pa1, bv_sav[0], o[1][0], 0, 0, 0);
                o[1][1] = __builtin_amdgcn_mfma_f32_16x16x32_bf16(pa1, bv_sav[1], o[1][1], 0, 0, 0);
                o[1][2] = __builtin_amdgcn_mfma_f32_16x16x32_bf16(pa1, bv_sav[2], o[1][2], 0, 0, 0);
                o[1][3] = __builtin_amdgcn_mfma_f32_16x16x32_bf16(pa1, bv_sav[3], o[1][3], 0, 0, 0);
                ol[1]   = __builtin_amdgcn_mfma_f32_16x16x32_bf16(pa1, bones, ol[1], 0, 0, 0);
            }
            // ---- QK^T for tile t
            const bf16_t* Kt = &Kb[t & 1][0];
            const bf16_t* Vt = &Vb[t & 1][0];
            bf16x8 bk0 = *(const bf16x8*)(Kt + lrow * 72 + quad * 8);
            bf16x8 bk1 = *(const bf16x8*)(Kt + lrow * 72 + 32 + quad * 8);
            bf16x8 bk2 = *(const bf16x8*)(Kt + (16 + lrow) * 72 + quad * 8);
            bf16x8 bk3 = *(const bf16x8*)(Kt + (16 + lrow) * 72 + 32 + quad * 8);
            floatx4 s00 = floatx4{0.f,0.f,0.f,0.f}, s01 = s00, s10 = s00, s11 = s00;
            s00 = __builtin_amdgcn_mfma_f32_16x16x32_bf16(aq[0][0], bk0, s00, 0, 0, 0);
            s00 = __builtin_amdgcn_mfma_f32_16x16x32_bf16(aq[0][1], bk1, s00, 0, 0, 0);
            s01 = __builtin_amdgcn_mfma_f32_16x16x32_bf16(aq[0][0], bk2, s01, 0, 0, 0);
            s01 = __builtin_amdgcn_mfma_f32_16x16x32_bf16(aq[0][1], bk3, s01, 0, 0, 0);
            s10 = __builtin_amdgcn_mfma_f32_16x16x32_bf16(aq[1][0], bk0, s10, 0, 0, 0);
            s10 = __builtin_amdgcn_mfma_f32_16x16x32_bf16(aq[1][1], bk1, s10, 0, 0, 0);
            s11 = __builtin_amdgcn_mfma_f32_16x16x32_bf16(aq[1][0], bk2, s11, 0, 0, 0);
            s11 = __builtin_amdgcn_mfma_f32_16x16x32_bf16(aq[1][1], bk3, s11, 0, 0, 0);

            bv_sav[0] = *(const bf16x8*)(Vt + (0  + lrow) * 40 + quad * 8);
            bv_sav[1] = *(const bf16x8*)(Vt + (16 + lrow) * 40 + quad * 8);
            bv_sav[2] = *(const bf16x8*)(Vt + (32 + lrow) * 40 + quad * 8);
            bv_sav[3] = *(const bf16x8*)(Vt + (48 + lrow) * 40 + quad * 8);

            uint32_t* P32 = (uint32_t*)(&Ps[w][t & 1][0]);
            if (t < kendl - 1) {            // unmasked tile
                for (int r = 0; r < 4; ++r) {
                    float e00 = __builtin_amdgcn_exp2f(s00[r]);
                    float e01 = __builtin_amdgcn_exp2f(s01[r]);
                    float e10 = __builtin_amdgcn_exp2f(s10[r]);
                    float e11 = __builtin_amdgcn_exp2f(s11[r]);
                    uint32_t pk0 = __builtin_amdgcn_perm(
                        __builtin_bit_cast(uint32_t, e01),
                        __builtin_bit_cast(uint32_t, e00), 0x07060302u);
                    uint32_t pk1 = __builtin_amdgcn_perm(
                        __builtin_bit_cast(uint32_t, e11),
                        __builtin_bit_cast(uint32_t, e10), 0x07060302u);
                    P32[(wrow0 + r) * 20 + lrow]      = pk0;
                    P32[(wrow0 + r + 16) * 20 + lrow] = pk1;
                }
            } else {                        // diagonal tile (keys start at q0)
                for (int r = 0; r < 4; ++r) {
                    bool keep = lrow <= quad * 4 + r;
                    float e00 = keep ? __builtin_amdgcn_exp2f(s00[r]) : 0.f;
                    float e01 = 0.f; (void)s01;
                    float e10 = __builtin_amdgcn_exp2f(s10[r]);
                    float e11 = keep ? __builtin_amdgcn_exp2f(s11[r]) : 0.f;
                    uint32_t pk0 = __builtin_amdgcn_perm(
                        __builtin_bit_cast(uint32_t, e01),
                        __builtin_bit_cast(uint32_t, e00), 0x07060302u);
                    uint32_t pk1 = __builtin_amdgcn_perm(
                        __builtin_bit_cast(uint32_t, e11),
                        __builtin_bit_cast(uint32_t, e10), 0x07060302u);
                    P32[(wrow0 + r) * 20 + lrow]      = pk0;
                    P32[(wrow0 + r + 16) * 20 + lrow] = pk1;
                }
            }
        }
        if (t + 1 < ct) {   // write staged K/V into the other buffer
            bf16_t* Kn = &Kb[(t + 1) & 1][0];
            bf16_t* Vn = &Vb[(t + 1) & 1][0];
            *(bf16x8*)(Kn + skey * 72 + scol)     = kra;
            *(bf16x8*)(Kn + skey * 72 + scol + 8) = krb;
            *(bf16x8*)(Vn + svrow * 40 + svcol)     = vra;
            *(bf16x8*)(Vn + svrow * 40 + svcol + 8) = vrb;
        }
    }

    // ---- final deferred PV (tile kw-1)
    asm volatile("s_waitcnt lgkmcnt(0)" ::: "memory");
    {
        const bf16_t* Pp = &Ps[w][(kw - 1) & 1][0];
        bf16x8 pa0 = *(const bf16x8*)(Pp + (size_t)lrow * PST2 + quad * 8);
        bf16x8 pa1 = *(const bf16x8*)(Pp + (size_t)(16 + lrow) * PST2 + quad * 8);
        o[0][0] = __builtin_amdgcn_mfma_f32_16x16x32_bf16(pa0, bv_sav[0], o[0][0], 0, 0, 0);
        o[0][1] = __builtin_amdgcn_mfma_f32_16x16x32_bf16(pa0, bv_sav[1], o[0][1], 0, 0, 0);
        o[0][2] = __builtin_amdgcn_mfma_f32_16x16x32_bf16(pa0, bv_sav[2], o[0][2], 0, 0, 0);
        o[0][3] = __builtin_amdgcn_mfma_f32_16x16x32_bf16(pa0, bv_sav[3], o[0][3], 0, 0, 0);
        ol[0]   = __builtin_amdgcn_mfma_f32_16x16x32_bf16(pa0, bones, ol[0], 0, 0, 0);
        o[1][0] = __builtin_amdgcn_mfma_f32_16x16x32_bf16(pa1, bv_sav[0], o[1][0], 0, 0, 0);
        o[1][1] = __builtin_amdgcn_mfma_f32_16x16x32_bf16(pa1, bv_sav[1], o[1][1], 0, 0, 0);
        o[1][2] = __builtin_amdgcn_mfma_f32_16x16x32_bf16(pa1, bv_sav[2], o[1][2], 0, 0, 0);
        o[1][3] = __builtin_amdgcn_mfma_f32_16x16x32_bf16(pa1, bv_sav[3], o[1][3], 0, 0, 0);
        ol[1]   = __builtin_amdgcn_mfma_f32_16x16x32_bf16(pa1, bones, ol[1], 0, 0, 0);
    }

    // ---- epilogue: plain stores to this block's private partial slots
    for (int tq = 0; tq < 2; ++tq)
        for (int r = 0; r < 4; ++r) {
            int q = q0 + tq * 16 + quad * 4 + r;
            if (cc == 1) {
                float* dst = o1 + ((size_t)(bh * 16 + qg - 16) * 64 + (q - qg * 64)) * 64 + lrow;
                for (int dc = 0; dc < 4; ++dc) dst[dc * 16] = o[tq][dc][r];
                if (lrow == 0) l1[(size_t)(bh * 16 + qg - 16) * 64 + (q - qg * 64)] = ol[tq][r];
            } else {
                float* dst = o0 + ((size_t)bh * TT + q) * HS + lrow;
                for (int dc = 0; dc < 4; ++dc) dst[dc * 16] = o[tq][dc][r];
                if (lrow == 0) l0[(size_t)bh * TT + q] = ol[tq][r];
            }
        }
}

// ---------------------------------------------------------------- normalize + combine
// yb[b,t,C] = (o0 [+ o1]) / (l0 [+ l1]), bf16. 8 d-elems/thread.
__global__ __launch_bounds__(256) void k_norm(const float* __restrict__ o0,
                                              const float* __restrict__ o1,
                                              const float* __restrict__ l0,
                                              const float* __restrict__ l1,
                                              bf16_t* __restrict__ yb) {
    int idx = blockIdx.x * 256 + threadIdx.x;      // over 32*2048*8
    int d8 = idx & 7;
    int q  = (idx >> 3) & (TT - 1);
    int bh = idx >> 14;
    const float* s0 = o0 + ((size_t)bh * TT + q) * HS + d8 * 8;
    float4 a = *(const float4*)(s0);
    float4 b = *(const float4*)(s0 + 4);
    float l = l0[(size_t)bh * TT + q];
    int qg = q >> 6;
    if (qg >= 16) {
        const float* s1 = o1 + ((size_t)(bh * 16 + qg - 16) * 64 + (q & 63)) * 64 + d8 * 8;
        float4 a1 = *(const float4*)(s1);
        float4 b1 = *(const float4*)(s1 + 4);
        a.x += a1.x; a.y += a1.y; a.z += a1.z; a.w += a1.w;
        b.x += b1.x; b.y += b1.y; b.z += b1.z; b.w += b1.w;
        l += l1[(size_t)(bh * 16 + qg - 16) * 64 + (q & 63)];
    }
    float inv = 1.0f / l;
    bf16x8 r;
    r[0] = f2bf(a.x * inv); r[1] = f2bf(a.y * inv);
    r[2] = f2bf(a.z * inv); r[3] = f2bf(a.w * inv);
    r[4] = f2bf(b.x * inv); r[5] = f2bf(b.y * inv);
    r[6] = f2bf(b.z * inv); r[7] = f2bf(b.w * inv);
    int bb = bh >> 4, h = bh & 15;
    *(bf16x8*)(yb + ((size_t)(bb * TT + q)) * CC + h * HS + d8 * 8) = r;
}

// ---------------------------------------------------------------- out GEMM (fp32 out + bias)
__global__ __launch_bounds__(256, 2) void k_gemm_out(const bf16_t* __restrict__ yin,
                                                     const bf16_t* __restrict__ Wt,
                                                     const float* __restrict__ bias,
                                                     float* __restrict__ out) {
    __shared__ bf16_t As[128 * 32];
    __shared__ bf16_t Bs[128 * 32];
    const int m0 = blockIdx.y * 128, n0 = blockIdx.x * 128;
    floatx4 acc[4][4];
    for (int i = 0; i < 4; ++i)
        for (int j = 0; j < 4; ++j)
            acc[i][j] = floatx4{0.f, 0.f, 0.f, 0.f};
    gemm_core(yin, Wt, As, Bs, m0, n0, CC, acc);

    const int tid = threadIdx.x, wave = tid >> 6, lane = tid & 63;
    const int quad = lane >> 4, lrow = lane & 15;
    const int wm = wave >> 1, wn = wave & 1;
    for (int i = 0; i < 4; ++i)
        for (int j = 0; j < 4; ++j) {
            int gn = n0 + wn * 64 + j * 16 + lrow;
            float bb = bias[gn];
            for (int r = 0; r < 4; ++r) {
                int gm = m0 + wm * 64 + i * 16 + quad * 4 + r;
                out[(size_t)gm * CC + gn] = acc[i][j][r] + bb;
            }
        }
}

// ---------------------------------------------------------------- launch
extern "C" void kernel_launch(void* const* d_in, const int* in_sizes, int n_in,
                              void* d_out, int out_size, void* d_ws, size_t ws_size,
                              hipStream_t stream) {
    (void)in_sizes; (void)n_in; (void)out_size; (void)ws_size;
    const float* x    = (const float*)d_in[0];  // [2,2048,1024] fp32
    const float* Wqkv = (const float*)d_in[1];  // [1024,3072]   fp32
    const float* Wout = (const float*)d_in[2];  // [1024,1024]   fp32
    const float* bout = (const float*)d_in[3];  // [1024]        fp32
    float* out = (float*)d_out;                 // [2,2048,1024] fp32

    bf16_t* xb  = (bf16_t*)d_ws;                        // [4096][1024]  8 MB
    bf16_t* Wt1 = xb + (size_t)MM * CC;                 // [3072][1024]  6 MB
    bf16_t* Wt2 = Wt1 + (size_t)N1 * CC;                // [1024][1024]  2 MB
    bf16_t* qb  = Wt2 + (size_t)CC * CC;                // [B,H,T,hs]    8 MB
    bf16_t* kb  = qb + (size_t)BB * HH * TT * HS;       // [B,H,T,hs]    8 MB
    bf16_t* vb  = kb + (size_t)BB * HH * TT * HS;       // [B,H,hs,T~]   8 MB (perm)
    bf16_t* yb  = vb + (size_t)BB * HH * TT * HS;       // [B,T,C] bf16  8 MB
    bf16_t* vn  = yb;            // natural V; dead after k_vperm, before yb born
    float*  o0  = (float*)d_out; // 16 MB partial-0; dead before k_gemm_out writes
    float*  o1  = (float*)xb;    // 8 MB partial-1; xb dead after k_gemm_qkv
    float*  l0  = (float*)Wt1;   // 256 KB; Wt1 dead after k_gemm_qkv
    float*  l1  = l0 + (size_t)BB * HH * TT;            // 128 KB

    k_pack<<<dim3((size_t)MM * CC / (256 * 8)), 256, 0, stream>>>(x, xb);
    k_transpose<<<dim3(N1 / 32, CC / 32), dim3(32, 8), 0, stream>>>(Wqkv, Wt1, CC, N1);
    k_transpose<<<dim3(CC / 32, CC / 32), dim3(32, 8), 0, stream>>>(Wout, Wt2, CC, CC);
    k_gemm_qkv<<<dim3(N1 / 128, MM / 128), 256, 0, stream>>>(xb, Wt1, qb, kb, vn);
    k_vperm<<<dim3(32 * 32), 256, 0, stream>>>(vn, vb);
    k_attn<<<dim3(48 * 32), 128, 0, stream>>>(qb, kb, vb, o0, o1, l0, l1);
    k_norm<<<dim3(BB * HH * TT * 8 / 256), 256, 0, stream>>>(o0, o1, l0, l1, yb);
    k_gemm_out<<<dim3(CC / 128, MM / 128), 256, 0, stream>>>(yb, Wt2, bout, out);
}

// Round 11
// 179.251 us; speedup vs baseline: 1.3134x; 1.0621x over previous
//
#include <hip/hip_runtime.h>
#include <cstdint>
#include <cstddef>

// Problem constants (from reference): B=2, T=2048, C=1024, H=16, hs=64
// Harness dtypes: inputs fp32, output fp32; internal compute bf16 MFMA.
#define BB 2
#define TT 2048
#define CC 1024
#define HH 16
#define HS 64
#define MM (BB*TT)      // 4096 rows
#define N1 (3*CC)       // 3072 qkv cols

// P-scratch row stride in elements (80 B/row)
#define PST2 40

// q prescale: hs^-0.5 * log2(e)  -> softmax_e(s) == softmax_2(s*log2e)
#define QSCALE 0.1803368801111243f

typedef __bf16 bf16_t;
typedef bf16_t bf16x8 __attribute__((ext_vector_type(8)));
typedef float  floatx4 __attribute__((ext_vector_type(4)));

__device__ __forceinline__ bf16_t f2bf(float f) {
    uint32_t u = __builtin_bit_cast(uint32_t, f);
    u += 0x7FFFu + ((u >> 16) & 1u);   // round-to-nearest-even
    unsigned short s = (unsigned short)(u >> 16);
    return __builtin_bit_cast(bf16_t, s);
}

__device__ __forceinline__ void load_lds16(const bf16_t* g, bf16_t* l) {
    __builtin_amdgcn_global_load_lds((__attribute__((address_space(1))) void*)g,
                                     (__attribute__((address_space(3))) void*)l,
                                     16, 0, 0);
}

// ---------------------------------------------------------------- prep (pack x + transpose both weights)
__device__ __forceinline__ void transpose_body(const float* __restrict__ src,
                                               bf16_t* __restrict__ dst,
                                               int R, int Ccol, int bx, int by,
                                               int tx, int ty, bf16_t (*tile)[33]) {
    int c0 = bx * 32, r0 = by * 32;
    for (int i = ty; i < 32; i += 8)
        tile[i][tx] = f2bf(src[(size_t)(r0 + i) * Ccol + c0 + tx]);
    __syncthreads();
    for (int i = ty; i < 32; i += 8)
        dst[(size_t)(c0 + i) * R + r0 + tx] = tile[tx][i];
}

__global__ __launch_bounds__(256) void k_prep(const float* __restrict__ x,
                                              const float* __restrict__ Wqkv,
                                              const float* __restrict__ Wout,
                                              bf16_t* __restrict__ xb,
                                              bf16_t* __restrict__ Wt1,
                                              bf16_t* __restrict__ Wt2) {
    __shared__ bf16_t tile[32][33];
    const int bid = blockIdx.x, tid = threadIdx.x;
    if (bid < 2048) {                       // pack x: 4M elems, 8/thread
        size_t i = ((size_t)bid * 256 + tid) * 8;
        float4 a = *(const float4*)(x + i);
        float4 b = *(const float4*)(x + i + 4);
        bf16x8 o;
        o[0] = f2bf(a.x); o[1] = f2bf(a.y); o[2] = f2bf(a.z); o[3] = f2bf(a.w);
        o[4] = f2bf(b.x); o[5] = f2bf(b.y); o[6] = f2bf(b.z); o[7] = f2bf(b.w);
        *(bf16x8*)(xb + i) = o;
    } else if (bid < 2048 + 3072) {         // Wqkv^T: grid (96,32)
        int bb = bid - 2048;
        transpose_body(Wqkv, Wt1, CC, N1, bb % 96, bb / 96, tid & 31, tid >> 5, tile);
    } else {                                // Wout^T: grid (32,32)
        int bb = bid - 5120;
        transpose_body(Wout, Wt2, CC, CC, bb & 31, bb >> 5, tid & 31, tid >> 5, tile);
    }
}

// ---------------------------------------------------------------- GEMM core
__device__ __forceinline__ void gemm_core(const bf16_t* __restrict__ A,
                                          const bf16_t* __restrict__ Bt,
                                          bf16_t* As, bf16_t* Bs,
                                          int m0, int n0, int K,
                                          floatx4 acc[4][4]) {
    const int tid = threadIdx.x;
    const int wave = tid >> 6, lane = tid & 63;
    const int quad = lane >> 4, lrow = lane & 15;
    const int wm = wave >> 1, wn = wave & 1;
    const int lsub = lane >> 2;
    const int kc = lane & 3;

    for (int kk = 0; kk < K; kk += 32) {
        for (int s = 0; s < 2; ++s) {
            int rg = wave * 2 + s;
            const bf16_t* ga = A  + (size_t)(m0 + rg * 16 + lsub) * K + kk + kc * 8;
            const bf16_t* gb = Bt + (size_t)(n0 + rg * 16 + lsub) * K + kk + kc * 8;
            load_lds16(ga, As + rg * 512);
            load_lds16(gb, Bs + rg * 512);
        }
        __syncthreads();
        bf16x8 af[4], bfr[4];
        for (int i = 0; i < 4; ++i)
            af[i] = *(const bf16x8*)(As + (wm * 64 + i * 16 + lrow) * 32 + quad * 8);
        for (int j = 0; j < 4; ++j)
            bfr[j] = *(const bf16x8*)(Bs + (wn * 64 + j * 16 + lrow) * 32 + quad * 8);
        for (int i = 0; i < 4; ++i)
            for (int j = 0; j < 4; ++j)
                acc[i][j] = __builtin_amdgcn_mfma_f32_16x16x32_bf16(af[i], bfr[j], acc[i][j], 0, 0, 0);
        __syncthreads();
    }
}

// ---------------------------------------------------------------- QKV GEMM (v fused: transposed + sigma-packed)
// q prescaled by QSCALE; k natural [B,H,T,hs]; v written DIRECTLY as
// vt[B,H,hs,T] with sigma(u)=(u&15)*2+(u>>4) per-32 key interleave, as dense
// 16B stores: the acc regs of i-pair (2a,2a+1) hold exactly sigma positions
// quad*8..quad*8+7 of the 32-key block (t=par*16+quad*4+r -> (quad*4+r)*2+par).
__global__ __launch_bounds__(256, 2) void k_gemm_qkv(const bf16_t* __restrict__ x,
                                                     const bf16_t* __restrict__ Wt,
                                                     bf16_t* __restrict__ qb,
                                                     bf16_t* __restrict__ kb,
                                                     bf16_t* __restrict__ vt) {
    __shared__ bf16_t As[128 * 32];
    __shared__ bf16_t Bs[128 * 32];
    const int m0 = blockIdx.y * 128, n0 = blockIdx.x * 128;
    floatx4 acc[4][4];
    for (int i = 0; i < 4; ++i)
        for (int j = 0; j < 4; ++j)
            acc[i][j] = floatx4{0.f, 0.f, 0.f, 0.f};
    gemm_core(x, Wt, As, Bs, m0, n0, CC, acc);

    const int tid = threadIdx.x, wave = tid >> 6, lane = tid & 63;
    const int quad = lane >> 4, lrow = lane & 15;
    const int wm = wave >> 1, wn = wave & 1;
    const int b = m0 >> 11;                  // whole block in one batch row
    for (int j = 0; j < 4; ++j) {
        int gn = n0 + wn * 64 + j * 16 + lrow;
        int which = gn >> 10, c = gn & 1023, h = c >> 6, d = c & 63;
        if (which == 0) {
            for (int i = 0; i < 4; ++i)
                for (int r = 0; r < 4; ++r) {
                    int t = (m0 & 2047) + wm * 64 + i * 16 + quad * 4 + r;
                    qb[((size_t)(b * HH + h) * TT + t) * HS + d] = f2bf(acc[i][j][r] * QSCALE);
                }
        } else if (which == 1) {
            for (int i = 0; i < 4; ++i)
                for (int r = 0; r < 4; ++r) {
                    int t = (m0 & 2047) + wm * 64 + i * 16 + quad * 4 + r;
                    kb[((size_t)(b * HH + h) * TT + t) * HS + d] = f2bf(acc[i][j][r]);
                }
        } else {
            for (int a = 0; a < 2; ++a) {
                bf16x8 pv;
                for (int r = 0; r < 4; ++r) {
                    pv[r * 2]     = f2bf(acc[2 * a][j][r]);
                    pv[r * 2 + 1] = f2bf(acc[2 * a + 1][j][r]);
                }
                int tb2 = (m0 & 2047) + wm * 64 + a * 32;
                *(bf16x8*)(vt + ((size_t)(b * HH + h) * HS + d) * TT + tb2 + quad * 8) = pv;
            }
        }
    }
}

// block schedule: (qg, c) sorted by trip count desc; c=-1 = unsplit (qg<16)
__device__ static const signed char ORD[48][2] = {
    {15,-1},{31,0},{31,1},{30,0},{30,1},
    {14,-1},{29,0},{29,1},{28,0},{28,1},
    {13,-1},{27,0},{27,1},{26,0},{26,1},
    {12,-1},{25,0},{25,1},{24,0},{24,1},
    {11,-1},{23,0},{23,1},{22,0},{22,1},
    {10,-1},{21,0},{21,1},{20,0},{20,1},
    { 9,-1},{19,0},{19,1},{18,0},{18,1},
    { 8,-1},{17,0},{17,1},{16,0},{16,1},
    { 7,-1},{ 6,-1},{ 5,-1},{ 4,-1},{ 3,-1},{ 2,-1},{ 1,-1},{ 0,-1}
};

// ---------------------------------------------------------------- attention (partials, no atomics)
// Unsplit (qg<16): ones-MFMA rowsum is lane-local (C-layout is col-
// independent) -> normalize in-register and write bf16 yb DIRECTLY.
// Split (qg>=16): c=0 -> o0/l0, c=1 -> o1/l1 plain stores; k_norm combines.
// P software-pipelined one tile (ping-pong parity buffers), no in-loop
// lgkmcnt(0). Cooperative double-buffered K/V LDS staging, 1 barrier/iter.
__global__ __launch_bounds__(128, 2) void k_attn(const bf16_t* __restrict__ qb,
                                                 const bf16_t* __restrict__ kb,
                                                 const bf16_t* __restrict__ vt,
                                                 bf16_t* __restrict__ yb,
                                                 float* __restrict__ o0,
                                                 float* __restrict__ o1,
                                                 float* __restrict__ l0,
                                                 float* __restrict__ l1) {
    __shared__ bf16_t Kb[2][32 * 72];      // key row stride 144B
    __shared__ bf16_t Vb[2][64 * 40];      // d row stride 80B
    __shared__ bf16_t Ps[2][2][32 * PST2]; // [wave][parity]
    const int tid = threadIdx.x;
    const int w = tid >> 6, lane = tid & 63;
    const int quad = lane >> 4, lrow = lane & 15;
    const int bh = blockIdx.x & 31;
    const int j = blockIdx.x >> 5;                 // 0..47
    const int qg = ORD[j][0];
    const int cc = ORD[j][1];                      // -1 = unsplit
    const int ct = (cc < 0) ? (2 * qg + 2) : (qg + 1);
    const int key0 = (cc == 1) ? (qg + 1) * 32 : 0;
    const int kendl = 2 * qg + w + 1 - ((cc == 1) ? (qg + 1) : 0);
    const int kw = min(kendl, ct);
    const int q0 = qg * 64 + w * 32;

    const bf16_t* Qg = qb + (size_t)bh * TT * HS;
    const bf16_t* Kg = kb + (size_t)bh * TT * HS;
    const bf16_t* Vg = vt + (size_t)bh * HS * TT;

    const int skey = tid >> 2, scol = (tid & 3) * 16;
    const int svrow = tid >> 1, svcol = (tid & 1) * 16;

    bf16x8 kra, krb, vra, vrb;
    {   // prestage tile 0
        const bf16_t* gk = Kg + (size_t)(key0 + skey) * HS + scol;
        kra = *(const bf16x8*)(gk);
        krb = *(const bf16x8*)(gk + 8);
        const bf16_t* gv = Vg + (size_t)svrow * TT + key0 + svcol;
        vra = *(const bf16x8*)(gv);
        vrb = *(const bf16x8*)(gv + 8);
        *(bf16x8*)(&Kb[0][skey * 72 + scol])     = kra;
        *(bf16x8*)(&Kb[0][skey * 72 + scol + 8]) = krb;
        *(bf16x8*)(&Vb[0][svrow * 40 + svcol])     = vra;
        *(bf16x8*)(&Vb[0][svrow * 40 + svcol + 8]) = vrb;
    }

    bf16x8 aq[2][2];
    for (int tq = 0; tq < 2; ++tq)
        for (int c = 0; c < 2; ++c)
            aq[tq][c] = *(const bf16x8*)(Qg + (size_t)(q0 + tq * 16 + lrow) * HS + c * 32 + quad * 8);

    const bf16_t onebf = __builtin_bit_cast(bf16_t, (unsigned short)0x3F80);
    bf16x8 bones = {onebf, onebf, onebf, onebf, onebf, onebf, onebf, onebf};

    floatx4 o[2][4];
    for (int tq = 0; tq < 2; ++tq)
        for (int dc = 0; dc < 4; ++dc) o[tq][dc] = floatx4{0.f, 0.f, 0.f, 0.f};
    floatx4 ol[2] = {floatx4{0.f,0.f,0.f,0.f}, floatx4{0.f,0.f,0.f,0.f}};

    bf16x8 bv_sav[4];
    const int wrow0 = quad * 4;

    for (int t = 0; t < ct; ++t) {
        __syncthreads();   // staging writes of t (done at end of t-1) visible
        if (t + 1 < ct) {  // post-barrier prefetch of next tile into regs
            const bf16_t* gk = Kg + (size_t)(key0 + (t + 1) * 32 + skey) * HS + scol;
            kra = *(const bf16x8*)(gk);
            krb = *(const bf16x8*)(gk + 8);
            const bf16_t* gv = Vg + (size_t)svrow * TT + key0 + (t + 1) * 32 + svcol;
            vra = *(const bf16x8*)(gv);
            vrb = *(const bf16x8*)(gv + 8);
        }
        if (t < kw) {
            // ---- deferred PV for tile t-1 (P from parity buffer, V from regs)
            if (t > 0) {
                const bf16_t* Pp = &Ps[w][(t - 1) & 1][0];
                bf16x8 pa0 = *(const bf16x8*)(Pp + (size_t)lrow * PST2 + quad * 8);
                bf16x8 pa1 = *(const bf16x8*)(Pp + (size_t)(16 + lrow) * PST2 + quad * 8);
                o[0][0] = __builtin_amdgcn_mfma_f32_16x16x32_bf16(pa0, bv_sav[0], o[0][0], 0, 0, 0);
                o[0][1] = __builtin_amdgcn_mfma_f32_16x16x32_bf16(pa0, bv_sav[1], o[0][1], 0, 0, 0);
                o[0][2] = __builtin_amdgcn_mfma_f32_16x16x32_bf16(pa0, bv_sav[2], o[0][2], 0, 0, 0);
                o[0][3] = __builtin_amdgcn_mfma_f32_16x16x32_bf16(pa0, bv_sav[3], o[0][3], 0, 0, 0);
                ol[0]   = __builtin_amdgcn_mfma_f32_16x16x32_bf16(pa0, bones, ol[0], 0, 0, 0);
                o[1][0] = __builtin_amdgcn_mfma_f32_16x16x32_bf16(pa1, bv_sav[0], o[1][0], 0, 0, 0);
                o[1][1] = __builtin_amdgcn_mfma_f32_16x16x32_bf16(pa1, bv_sav[1], o[1][1], 0, 0, 0);
                o[1][2] = __builtin_amdgcn_mfma_f32_16x16x32_bf16(pa1, bv_sav[2], o[1][2], 0, 0, 0);
                o[1][3] = __builtin_amdgcn_mfma_f32_16x16x32_bf16(pa1, bv_sav[3], o[1][3], 0, 0, 0);
                ol[1]   = __builtin_amdgcn_mfma_f32_16x16x32_bf16(pa1, bones, ol[1], 0, 0, 0);
            }
            // ---- QK^T for tile t
            const bf16_t* Kt = &Kb[t & 1][0];
            const bf16_t* Vt = &Vb[t & 1][0];
            bf16x8 bk0 = *(const bf16x8*)(Kt + lrow * 72 + quad * 8);
            bf16x8 bk1 = *(const bf16x8*)(Kt + lrow * 72 + 32 + quad * 8);
            bf16x8 bk2 = *(const bf16x8*)(Kt + (16 + lrow) * 72 + quad * 8);
            bf16x8 bk3 = *(const bf16x8*)(Kt + (16 + lrow) * 72 + 32 + quad * 8);
            floatx4 s00 = floatx4{0.f,0.f,0.f,0.f}, s01 = s00, s10 = s00, s11 = s00;
            s00 = __builtin_amdgcn_mfma_f32_16x16x32_bf16(aq[0][0], bk0, s00, 0, 0, 0);
            s00 = __builtin_amdgcn_mfma_f32_16x16x32_bf16(aq[0][1], bk1, s00, 0, 0, 0);
            s01 = __builtin_amdgcn_mfma_f32_16x16x32_bf16(aq[0][0], bk2, s01, 0, 0, 0);
            s01 = __builtin_amdgcn_mfma_f32_16x16x32_bf16(aq[0][1], bk3, s01, 0, 0, 0);
            s10 = __builtin_amdgcn_mfma_f32_16x16x32_bf16(aq[1][0], bk0, s10, 0, 0, 0);
            s10 = __builtin_amdgcn_mfma_f32_16x16x32_bf16(aq[1][1], bk1, s10, 0, 0, 0);
            s11 = __builtin_amdgcn_mfma_f32_16x16x32_bf16(aq[1][0], bk2, s11, 0, 0, 0);
            s11 = __builtin_amdgcn_mfma_f32_16x16x32_bf16(aq[1][1], bk3, s11, 0, 0, 0);

            bv_sav[0] = *(const bf16x8*)(Vt + (0  + lrow) * 40 + quad * 8);
            bv_sav[1] = *(const bf16x8*)(Vt + (16 + lrow) * 40 + quad * 8);
            bv_sav[2] = *(const bf16x8*)(Vt + (32 + lrow) * 40 + quad * 8);
            bv_sav[3] = *(const bf16x8*)(Vt + (48 + lrow) * 40 + quad * 8);

            uint32_t* P32 = (uint32_t*)(&Ps[w][t & 1][0]);
            if (t < kendl - 1) {            // unmasked tile
                for (int r = 0; r < 4; ++r) {
                    float e00 = __builtin_amdgcn_exp2f(s00[r]);
                    float e01 = __builtin_amdgcn_exp2f(s01[r]);
                    float e10 = __builtin_amdgcn_exp2f(s10[r]);
                    float e11 = __builtin_amdgcn_exp2f(s11[r]);
                    uint32_t pk0 = __builtin_amdgcn_perm(
                        __builtin_bit_cast(uint32_t, e01),
                        __builtin_bit_cast(uint32_t, e00), 0x07060302u);
                    uint32_t pk1 = __builtin_amdgcn_perm(
                        __builtin_bit_cast(uint32_t, e11),
                        __builtin_bit_cast(uint32_t, e10), 0x07060302u);
                    P32[(wrow0 + r) * 20 + lrow]      = pk0;
                    P32[(wrow0 + r + 16) * 20 + lrow] = pk1;
                }
            } else {                        // diagonal tile (keys start at q0)
                for (int r = 0; r < 4; ++r) {
                    bool keep = lrow <= quad * 4 + r;
                    float e00 = keep ? __builtin_amdgcn_exp2f(s00[r]) : 0.f;
                    float e01 = 0.f; (void)s01;
                    float e10 = __builtin_amdgcn_exp2f(s10[r]);
                    float e11 = keep ? __builtin_amdgcn_exp2f(s11[r]) : 0.f;
                    uint32_t pk0 = __builtin_amdgcn_perm(
                        __builtin_bit_cast(uint32_t, e01),
                        __builtin_bit_cast(uint32_t, e00), 0x07060302u);
                    uint32_t pk1 = __builtin_amdgcn_perm(
                        __builtin_bit_cast(uint32_t, e11),
                        __builtin_bit_cast(uint32_t, e10), 0x07060302u);
                    P32[(wrow0 + r) * 20 + lrow]      = pk0;
                    P32[(wrow0 + r + 16) * 20 + lrow] = pk1;
                }
            }
        }
        if (t + 1 < ct) {   // write staged K/V into the other buffer
            bf16_t* Kn = &Kb[(t + 1) & 1][0];
            bf16_t* Vn = &Vb[(t + 1) & 1][0];
            *(bf16x8*)(Kn + skey * 72 + scol)     = kra;
            *(bf16x8*)(Kn + skey * 72 + scol + 8) = krb;
            *(bf16x8*)(Vn + svrow * 40 + svcol)     = vra;
            *(bf16x8*)(Vn + svrow * 40 + svcol + 8) = vrb;
        }
    }

    // ---- final deferred PV (tile kw-1)
    asm volatile("s_waitcnt lgkmcnt(0)" ::: "memory");
    {
        const bf16_t* Pp = &Ps[w][(kw - 1) & 1][0];
        bf16x8 pa0 = *(const bf16x8*)(Pp + (size_t)lrow * PST2 + quad * 8);
        bf16x8 pa1 = *(const bf16x8*)(Pp + (size_t)(16 + lrow) * PST2 + quad * 8);
        o[0][0] = __builtin_amdgcn_mfma_f32_16x16x32_bf16(pa0, bv_sav[0], o[0][0], 0, 0, 0);
        o[0][1] = __builtin_amdgcn_mfma_f32_16x16x32_bf16(pa0, bv_sav[1], o[0][1], 0, 0, 0);
        o[0][2] = __builtin_amdgcn_mfma_f32_16x16x32_bf16(pa0, bv_sav[2], o[0][2], 0, 0, 0);
        o[0][3] = __builtin_amdgcn_mfma_f32_16x16x32_bf16(pa0, bv_sav[3], o[0][3], 0, 0, 0);
        ol[0]   = __builtin_amdgcn_mfma_f32_16x16x32_bf16(pa0, bones, ol[0], 0, 0, 0);
        o[1][0] = __builtin_amdgcn_mfma_f32_16x16x32_bf16(pa1, bv_sav[0], o[1][0], 0, 0, 0);
        o[1][1] = __builtin_amdgcn_mfma_f32_16x16x32_bf16(pa1, bv_sav[1], o[1][1], 0, 0, 0);
        o[1][2] = __builtin_amdgcn_mfma_f32_16x16x32_bf16(pa1, bv_sav[2], o[1][2], 0, 0, 0);
        o[1][3] = __builtin_amdgcn_mfma_f32_16x16x32_bf16(pa1, bv_sav[3], o[1][3], 0, 0, 0);
        ol[1]   = __builtin_amdgcn_mfma_f32_16x16x32_bf16(pa1, bones, ol[1], 0, 0, 0);
    }

    // ---- epilogue
    if (cc < 0) {           // unsplit: normalize locally, write yb directly
        const int b = bh >> 4, h = bh & 15;
        for (int tq = 0; tq < 2; ++tq)
            for (int r = 0; r < 4; ++r) {
                float inv = 1.0f / ol[tq][r];
                int q = q0 + tq * 16 + quad * 4 + r;
                for (int dc = 0; dc < 4; ++dc)
                    yb[(size_t)(b * TT + q) * CC + h * HS + dc * 16 + lrow] =
                        f2bf(o[tq][dc][r] * inv);
            }
    } else if (cc == 1) {   // split back half
        for (int tq = 0; tq < 2; ++tq)
            for (int r = 0; r < 4; ++r) {
                int q = q0 + tq * 16 + quad * 4 + r;
                float* dst = o1 + ((size_t)(bh * 16 + qg - 16) * 64 + (q - qg * 64)) * 64 + lrow;
                for (int dc = 0; dc < 4; ++dc) dst[dc * 16] = o[tq][dc][r];
                if (lrow == 0) l1[(size_t)(bh * 16 + qg - 16) * 64 + (q - qg * 64)] = ol[tq][r];
            }
    } else {                // split front half
        for (int tq = 0; tq < 2; ++tq)
            for (int r = 0; r < 4; ++r) {
                int q = q0 + tq * 16 + quad * 4 + r;
                float* dst = o0 + ((size_t)bh * TT + q) * HS + lrow;
                for (int dc = 0; dc < 4; ++dc) dst[dc * 16] = o[tq][dc][r];
                if (lrow == 0) l0[(size_t)bh * TT + q] = ol[tq][r];
            }
    }
}

// ---------------------------------------------------------------- normalize + combine (split rows only, q>=1024)
__global__ __launch_bounds__(256) void k_norm(const float* __restrict__ o0,
                                              const float* __restrict__ o1,
                                              const float* __restrict__ l0,
                                              const float* __restrict__ l1,
                                              bf16_t* __restrict__ yb) {
    int idx = blockIdx.x * 256 + threadIdx.x;      // over 32 bh x 1024 q x 8
    int d8 = idx & 7;
    int q  = 1024 + ((idx >> 3) & 1023);
    int bh = idx >> 13;
    int qg = q >> 6;
    const float* s0 = o0 + ((size_t)bh * TT + q) * HS + d8 * 8;
    const float* s1 = o1 + ((size_t)(bh * 16 + qg - 16) * 64 + (q & 63)) * 64 + d8 * 8;
    float4 a = *(const float4*)(s0);
    float4 b = *(const float4*)(s0 + 4);
    float4 a1 = *(const float4*)(s1);
    float4 b1 = *(const float4*)(s1 + 4);
    a.x += a1.x; a.y += a1.y; a.z += a1.z; a.w += a1.w;
    b.x += b1.x; b.y += b1.y; b.z += b1.z; b.w += b1.w;
    float l = l0[(size_t)bh * TT + q] + l1[(size_t)(bh * 16 + qg - 16) * 64 + (q & 63)];
    float inv = 1.0f / l;
    bf16x8 r;
    r[0] = f2bf(a.x * inv); r[1] = f2bf(a.y * inv);
    r[2] = f2bf(a.z * inv); r[3] = f2bf(a.w * inv);
    r[4] = f2bf(b.x * inv); r[5] = f2bf(b.y * inv);
    r[6] = f2bf(b.z * inv); r[7] = f2bf(b.w * inv);
    int bb = bh >> 4, h = bh & 15;
    *(bf16x8*)(yb + ((size_t)(bb * TT + q)) * CC + h * HS + d8 * 8) = r;
}

// ---------------------------------------------------------------- out GEMM (fp32 out + bias)
__global__ __launch_bounds__(256, 2) void k_gemm_out(const bf16_t* __restrict__ yin,
                                                     const bf16_t* __restrict__ Wt,
                                                     const float* __restrict__ bias,
                                                     float* __restrict__ out) {
    __shared__ bf16_t As[128 * 32];
    __shared__ bf16_t Bs[128 * 32];
    const int m0 = blockIdx.y * 128, n0 = blockIdx.x * 128;
    floatx4 acc[4][4];
    for (int i = 0; i < 4; ++i)
        for (int j = 0; j < 4; ++j)
            acc[i][j] = floatx4{0.f, 0.f, 0.f, 0.f};
    gemm_core(yin, Wt, As, Bs, m0, n0, CC, acc);

    const int tid = threadIdx.x, wave = tid >> 6, lane = tid & 63;
    const int quad = lane >> 4, lrow = lane & 15;
    const int wm = wave >> 1, wn = wave & 1;
    for (int i = 0; i < 4; ++i)
        for (int j = 0; j < 4; ++j) {
            int gn = n0 + wn * 64 + j * 16 + lrow;
            float bb = bias[gn];
            for (int r = 0; r < 4; ++r) {
                int gm = m0 + wm * 64 + i * 16 + quad * 4 + r;
                out[(size_t)gm * CC + gn] = acc[i][j][r] + bb;
            }
        }
}

// ---------------------------------------------------------------- launch
extern "C" void kernel_launch(void* const* d_in, const int* in_sizes, int n_in,
                              void* d_out, int out_size, void* d_ws, size_t ws_size,
                              hipStream_t stream) {
    (void)in_sizes; (void)n_in; (void)out_size; (void)ws_size;
    const float* x    = (const float*)d_in[0];  // [2,2048,1024] fp32
    const float* Wqkv = (const float*)d_in[1];  // [1024,3072]   fp32
    const float* Wout = (const float*)d_in[2];  // [1024,1024]   fp32
    const float* bout = (const float*)d_in[3];  // [1024]        fp32
    float* out = (float*)d_out;                 // [2,2048,1024] fp32

    bf16_t* xb  = (bf16_t*)d_ws;                        // [4096][1024]  8 MB
    bf16_t* Wt1 = xb + (size_t)MM * CC;                 // [3072][1024]  6 MB
    bf16_t* Wt2 = Wt1 + (size_t)N1 * CC;                // [1024][1024]  2 MB
    bf16_t* qb  = Wt2 + (size_t)CC * CC;                // [B,H,T,hs]    8 MB
    bf16_t* kb  = qb + (size_t)BB * HH * TT * HS;       // [B,H,T,hs]    8 MB
    bf16_t* vb  = kb + (size_t)BB * HH * TT * HS;       // [B,H,hs,T~]   8 MB (perm)
    bf16_t* yb  = vb + (size_t)BB * HH * TT * HS;       // [B,T,C] bf16  8 MB
    float*  o0  = (float*)d_out; // 16 MB partial-0; dead before k_gemm_out writes
    float*  o1  = (float*)xb;    // 8 MB partial-1; xb dead after k_gemm_qkv
    float*  l0  = (float*)Wt1;   // 256 KB; Wt1 dead after k_gemm_qkv
    float*  l1  = l0 + (size_t)BB * HH * TT;            // 128 KB

    k_prep<<<dim3(2048 + 3072 + 1024), 256, 0, stream>>>(x, Wqkv, Wout, xb, Wt1, Wt2);
    k_gemm_qkv<<<dim3(N1 / 128, MM / 128), 256, 0, stream>>>(xb, Wt1, qb, kb, vb);
    k_attn<<<dim3(48 * 32), 128, 0, stream>>>(qb, kb, vb, yb, o0, o1, l0, l1);
    k_norm<<<dim3(1024), 256, 0, stream>>>(o0, o1, l0, l1, yb);
    k_gemm_out<<<dim3(CC / 128, MM / 128), 256, 0, stream>>>(yb, Wt2, bout, out);
}